// Round 3
// baseline (629.594 us; speedup 1.0000x reference)
//
#include <hip/hip_runtime.h>

#define IN_SZ 8192
#define OUT_SZ 8192

// sigmoid(2.0)
#define SIG_TAU 0.8807970779778823f

// gemv split-K geometry
#define GEMV_ROWS   64
#define GEMV_CHUNKS (IN_SZ / GEMV_ROWS)           // 128
#define GEMV_TILES  (OUT_SZ / 1024)               // 8 col tiles of 1024
#define GEMV_BLOCKS (GEMV_CHUNKS * GEMV_TILES)    // 1024
#define JUP_BLOCKS  IN_SZ                         // 8192

typedef float v4f __attribute__((ext_vector_type(4)));

// ---------------------------------------------------------------------------
// Fused main kernel.
//   blocks [0, GEMV_BLOCKS): split-K gemv partials -> ws (atomic-free)
//   blocks [GEMV_BLOCKS, GEMV_BLOCKS+JUP_BLOCKS): eligibility-trace update
// Both streams share HBM concurrently instead of serializing as 2 launches.
// J path uses nontemporal hints (zero reuse) so W can stay resident in the
// 256 MB Infinity Cache across bench iterations.
// ---------------------------------------------------------------------------
__global__ __launch_bounds__(256) void main_kernel(
        const float* __restrict__ x,
        const float* __restrict__ J,
        const float* __restrict__ W,
        float* __restrict__ Jout,
        float* __restrict__ partial) {
    const int bid = blockIdx.x;
    const int tid = threadIdx.x;

    if (bid < GEMV_BLOCKS) {
        // ------- gemv partial: chunk of 64 rows x tile of 1024 cols -------
        __shared__ float xs[GEMV_ROWS];
        const int tile  = bid & (GEMV_TILES - 1);
        const int chunk = bid / GEMV_TILES;
        const int col0  = tile * 1024 + tid * 4;
        const int row0  = chunk * GEMV_ROWS;

        if (tid < GEMV_ROWS) xs[tid] = x[row0 + tid];
        __syncthreads();

        float4 acc = make_float4(0.f, 0.f, 0.f, 0.f);
        const float* wp = W + (size_t)row0 * OUT_SZ + col0;
#pragma unroll 8
        for (int r = 0; r < GEMV_ROWS; ++r) {
            float4 w = *(const float4*)wp;     // cacheable: keep W in L3
            float xi = xs[r];
            acc.x += xi * w.x;
            acc.y += xi * w.y;
            acc.z += xi * w.z;
            acc.w += xi * w.w;
            wp += OUT_SZ;
        }
        // one coalesced partial write, no atomics, no zero-init needed
        *(float4*)(partial + (size_t)chunk * OUT_SZ + col0) = acc;
    } else {
        // ------- eligibility trace: J_new = sig_tau*J + x[row] -------
        const int row = bid - GEMV_BLOCKS;
        const float xi = x[row];
        const v4f* jp = (const v4f*)(J + (size_t)row * OUT_SZ);
        v4f* op = (v4f*)(Jout + (size_t)row * OUT_SZ);
#pragma unroll
        for (int c = 0; c < OUT_SZ / 4 / 256; ++c) {
            v4f v = __builtin_nontemporal_load(&jp[c * 256 + tid]);
            v.x = SIG_TAU * v.x + xi;
            v.y = SIG_TAU * v.y + xi;
            v.z = SIG_TAU * v.z + xi;
            v.w = SIG_TAU * v.w + xi;
            __builtin_nontemporal_store(v, &op[c * 256 + tid]);
        }
    }
}

// ---------------------------------------------------------------------------
// Finalize: reduce split-K partials, cell update, spike output.
//   I      = sum_c partial[c][j]        (128 coalesced loads / thread)
//   u_new  = sig_tau*u[j] + I
//   s      = (u_new - 1 > 0)
//   out[j]            = u_new - s
//   out[OUT+IN*OUT+j] = s
// ---------------------------------------------------------------------------
__global__ __launch_bounds__(256) void finalize_reduce_kernel(
        const float* __restrict__ u,
        const float* __restrict__ partial,
        float* __restrict__ out) {
    const int j = blockIdx.x * blockDim.x + threadIdx.x;
    if (j >= OUT_SZ) return;
    float a0 = 0.f, a1 = 0.f, a2 = 0.f, a3 = 0.f;
#pragma unroll 4
    for (int c = 0; c < GEMV_CHUNKS; c += 4) {
        a0 += partial[(size_t)(c + 0) * OUT_SZ + j];
        a1 += partial[(size_t)(c + 1) * OUT_SZ + j];
        a2 += partial[(size_t)(c + 2) * OUT_SZ + j];
        a3 += partial[(size_t)(c + 3) * OUT_SZ + j];
    }
    float I     = (a0 + a1) + (a2 + a3);
    float u_new = SIG_TAU * u[j] + I;
    float s     = (u_new - 1.0f > 0.0f) ? 1.0f : 0.0f;
    out[j] = u_new - s;
    out[(size_t)OUT_SZ + (size_t)IN_SZ * OUT_SZ + j] = s;
}

// ---------------------------------------------------------------------------
// Fallback path (ws too small): previous proven atomic-based version.
// ---------------------------------------------------------------------------
__global__ void zeroI_kernel(float* __restrict__ I) {
    int j = blockIdx.x * blockDim.x + threadIdx.x;
    if (j < OUT_SZ) I[j] = 0.0f;
}

template <int ROWS>
__global__ void gemv_partial_atomic_kernel(const float* __restrict__ x,
                                           const float* __restrict__ W,
                                           float* __restrict__ Iacc) {
    __shared__ float xs[ROWS];
    const int tid  = threadIdx.x;
    const int col0 = blockIdx.x * 1024 + tid * 4;
    const int row0 = blockIdx.y * ROWS;

    if (tid < ROWS) xs[tid] = x[row0 + tid];
    __syncthreads();

    float4 acc = make_float4(0.f, 0.f, 0.f, 0.f);
    const float* wp = W + (size_t)row0 * OUT_SZ + col0;
#pragma unroll 8
    for (int r = 0; r < ROWS; ++r) {
        float4 w = *(const float4*)wp;
        float xi = xs[r];
        acc.x += xi * w.x;
        acc.y += xi * w.y;
        acc.z += xi * w.z;
        acc.w += xi * w.w;
        wp += OUT_SZ;
    }
    atomicAdd(&Iacc[col0 + 0], acc.x);
    atomicAdd(&Iacc[col0 + 1], acc.y);
    atomicAdd(&Iacc[col0 + 2], acc.z);
    atomicAdd(&Iacc[col0 + 3], acc.w);
}

__global__ void finalize_kernel(const float* __restrict__ u,
                                float* __restrict__ out) {
    int j = blockIdx.x * blockDim.x + threadIdx.x;
    if (j >= OUT_SZ) return;
    float I     = out[j];
    float u_new = SIG_TAU * u[j] + I;
    float s     = (u_new - 1.0f > 0.0f) ? 1.0f : 0.0f;
    out[j] = u_new - s;
    out[(size_t)OUT_SZ + (size_t)IN_SZ * OUT_SZ + j] = s;
}

__global__ void jup_kernel(const float* __restrict__ x,
                           const float* __restrict__ J,
                           float* __restrict__ Jout) {
    const int row = blockIdx.x;
    const float xi = x[row];
    const float4* jp = (const float4*)(J + (size_t)row * OUT_SZ);
    float4* op = (float4*)(Jout + (size_t)row * OUT_SZ);
    const int tid = threadIdx.x;
#pragma unroll
    for (int c = 0; c < OUT_SZ / 4 / 256; ++c) {
        float4 v = jp[c * 256 + tid];
        v.x = SIG_TAU * v.x + xi;
        v.y = SIG_TAU * v.y + xi;
        v.z = SIG_TAU * v.z + xi;
        v.w = SIG_TAU * v.w + xi;
        op[c * 256 + tid] = v;
    }
}

extern "C" void kernel_launch(void* const* d_in, const int* in_sizes, int n_in,
                              void* d_out, int out_size, void* d_ws, size_t ws_size,
                              hipStream_t stream) {
    const float* x = (const float*)d_in[0];   // [IN_SZ]
    const float* u = (const float*)d_in[1];   // [OUT_SZ]
    const float* J = (const float*)d_in[2];   // [IN_SZ, OUT_SZ]
    const float* W = (const float*)d_in[3];   // [IN_SZ, OUT_SZ]
    float* out = (float*)d_out;

    const size_t ws_needed = (size_t)GEMV_CHUNKS * OUT_SZ * sizeof(float); // 4 MB

    if (d_ws != nullptr && ws_size >= ws_needed) {
        float* partial = (float*)d_ws;
        main_kernel<<<GEMV_BLOCKS + JUP_BLOCKS, 256, 0, stream>>>(
            x, J, W, out + OUT_SZ, partial);
        finalize_reduce_kernel<<<(OUT_SZ + 255) / 256, 256, 0, stream>>>(
            u, partial, out);
    } else {
        // fallback: previous verified 4-launch atomic path
        jup_kernel<<<IN_SZ, 256, 0, stream>>>(x, J, out + OUT_SZ);
        zeroI_kernel<<<(OUT_SZ + 255) / 256, 256, 0, stream>>>(out);
        gemv_partial_atomic_kernel<64><<<dim3(OUT_SZ / 1024, IN_SZ / 64), 256, 0, stream>>>(x, W, out);
        finalize_kernel<<<(OUT_SZ + 255) / 256, 256, 0, stream>>>(u, out);
    }
}

// Round 4
// 613.194 us; speedup vs baseline: 1.0267x; 1.0267x over previous
//
#include <hip/hip_runtime.h>

#define IN_SZ 8192
#define OUT_SZ 8192

// sigmoid(2.0)
#define SIG_TAU 0.8807970779778823f

// gemv split-K geometry
#define GEMV_ROWS   64
#define GEMV_CHUNKS (IN_SZ / GEMV_ROWS)           // 128
#define GEMV_TILES  (OUT_SZ / 1024)               // 8 col tiles of 1024
#define GEMV_BLOCKS (GEMV_CHUNKS * GEMV_TILES)    // 1024

typedef float v4f __attribute__((ext_vector_type(4)));

// ---------------------------------------------------------------------------
// Eligibility-trace update, half of the rows, A/B-instrumented.
//   J_new[row][j] = sig_tau * J[row][j] + x[row]
// One block per row, 256 threads, 8 float4 per thread.
// ALL 8 loads are issued into registers before any store (8-deep MLP —
// fixes the VGPR=28 serial load/store chain seen in round 3).
// NT=true uses nontemporal hints (bypass L2/L3 allocation, protects W
// residency); NT=false is the plain-cached control. rocprof per-dispatch
// dur + FETCH/WRITE gives a clean within-probe A/B at identical work.
// ---------------------------------------------------------------------------
template <bool NT>
__global__ __launch_bounds__(256) void jup_half_kernel(
        const float* __restrict__ x,
        const float* __restrict__ J,
        float* __restrict__ Jout,
        int row0) {
    const int row = row0 + blockIdx.x;
    const int tid = threadIdx.x;
    const float xi = x[row];
    const v4f* jp = (const v4f*)(J + (size_t)row * OUT_SZ);
    v4f* op = (v4f*)(Jout + (size_t)row * OUT_SZ);

    v4f v[8];
#pragma unroll
    for (int c = 0; c < 8; ++c) {
        if (NT) v[c] = __builtin_nontemporal_load(&jp[c * 256 + tid]);
        else    v[c] = jp[c * 256 + tid];
    }
#pragma unroll
    for (int c = 0; c < 8; ++c) {
        v4f r;
        r.x = SIG_TAU * v[c].x + xi;
        r.y = SIG_TAU * v[c].y + xi;
        r.z = SIG_TAU * v[c].z + xi;
        r.w = SIG_TAU * v[c].w + xi;
        if (NT) __builtin_nontemporal_store(r, &op[c * 256 + tid]);
        else    op[c * 256 + tid] = r;
    }
}

// ---------------------------------------------------------------------------
// Split-K gemv partials, atomic-free, own dispatch so its FETCH_SIZE
// directly measures W's L3 residency.
// ---------------------------------------------------------------------------
__global__ __launch_bounds__(256) void gemv_partial_kernel(
        const float* __restrict__ x,
        const float* __restrict__ W,
        float* __restrict__ partial) {
    __shared__ float xs[GEMV_ROWS];
    const int bid   = blockIdx.x;
    const int tid   = threadIdx.x;
    const int tile  = bid & (GEMV_TILES - 1);
    const int chunk = bid / GEMV_TILES;
    const int col0  = tile * 1024 + tid * 4;
    const int row0  = chunk * GEMV_ROWS;

    if (tid < GEMV_ROWS) xs[tid] = x[row0 + tid];
    __syncthreads();

    float4 acc = make_float4(0.f, 0.f, 0.f, 0.f);
    const float* wp = W + (size_t)row0 * OUT_SZ + col0;
#pragma unroll 8
    for (int r = 0; r < GEMV_ROWS; ++r) {
        float4 w = *(const float4*)wp;     // cacheable: keep W in L3
        float xi = xs[r];
        acc.x += xi * w.x;
        acc.y += xi * w.y;
        acc.z += xi * w.z;
        acc.w += xi * w.w;
        wp += OUT_SZ;
    }
    *(float4*)(partial + (size_t)chunk * OUT_SZ + col0) = acc;
}

// ---------------------------------------------------------------------------
// Finalize: reduce split-K partials, cell update, spike output.
// ---------------------------------------------------------------------------
__global__ __launch_bounds__(256) void finalize_reduce_kernel(
        const float* __restrict__ u,
        const float* __restrict__ partial,
        float* __restrict__ out) {
    const int j = blockIdx.x * blockDim.x + threadIdx.x;
    if (j >= OUT_SZ) return;
    float a0 = 0.f, a1 = 0.f, a2 = 0.f, a3 = 0.f;
#pragma unroll 4
    for (int c = 0; c < GEMV_CHUNKS; c += 4) {
        a0 += partial[(size_t)(c + 0) * OUT_SZ + j];
        a1 += partial[(size_t)(c + 1) * OUT_SZ + j];
        a2 += partial[(size_t)(c + 2) * OUT_SZ + j];
        a3 += partial[(size_t)(c + 3) * OUT_SZ + j];
    }
    float I     = (a0 + a1) + (a2 + a3);
    float u_new = SIG_TAU * u[j] + I;
    float s     = (u_new - 1.0f > 0.0f) ? 1.0f : 0.0f;
    out[j] = u_new - s;
    out[(size_t)OUT_SZ + (size_t)IN_SZ * OUT_SZ + j] = s;
}

// ---------------------------------------------------------------------------
// Fallback path (ws too small): previous verified atomic-based version.
// ---------------------------------------------------------------------------
__global__ void zeroI_kernel(float* __restrict__ I) {
    int j = blockIdx.x * blockDim.x + threadIdx.x;
    if (j < OUT_SZ) I[j] = 0.0f;
}

template <int ROWS>
__global__ void gemv_partial_atomic_kernel(const float* __restrict__ x,
                                           const float* __restrict__ W,
                                           float* __restrict__ Iacc) {
    __shared__ float xs[ROWS];
    const int tid  = threadIdx.x;
    const int col0 = blockIdx.x * 1024 + tid * 4;
    const int row0 = blockIdx.y * ROWS;

    if (tid < ROWS) xs[tid] = x[row0 + tid];
    __syncthreads();

    float4 acc = make_float4(0.f, 0.f, 0.f, 0.f);
    const float* wp = W + (size_t)row0 * OUT_SZ + col0;
#pragma unroll 8
    for (int r = 0; r < ROWS; ++r) {
        float4 w = *(const float4*)wp;
        float xi = xs[r];
        acc.x += xi * w.x;
        acc.y += xi * w.y;
        acc.z += xi * w.z;
        acc.w += xi * w.w;
        wp += OUT_SZ;
    }
    atomicAdd(&Iacc[col0 + 0], acc.x);
    atomicAdd(&Iacc[col0 + 1], acc.y);
    atomicAdd(&Iacc[col0 + 2], acc.z);
    atomicAdd(&Iacc[col0 + 3], acc.w);
}

__global__ void finalize_kernel(const float* __restrict__ u,
                                float* __restrict__ out) {
    int j = blockIdx.x * blockDim.x + threadIdx.x;
    if (j >= OUT_SZ) return;
    float I     = out[j];
    float u_new = SIG_TAU * u[j] + I;
    float s     = (u_new - 1.0f > 0.0f) ? 1.0f : 0.0f;
    out[j] = u_new - s;
    out[(size_t)OUT_SZ + (size_t)IN_SZ * OUT_SZ + j] = s;
}

__global__ void jup_kernel(const float* __restrict__ x,
                           const float* __restrict__ J,
                           float* __restrict__ Jout) {
    const int row = blockIdx.x;
    const float xi = x[row];
    const float4* jp = (const float4*)(J + (size_t)row * OUT_SZ);
    float4* op = (float4*)(Jout + (size_t)row * OUT_SZ);
    const int tid = threadIdx.x;
#pragma unroll
    for (int c = 0; c < OUT_SZ / 4 / 256; ++c) {
        float4 v = jp[c * 256 + tid];
        v.x = SIG_TAU * v.x + xi;
        v.y = SIG_TAU * v.y + xi;
        v.z = SIG_TAU * v.z + xi;
        v.w = SIG_TAU * v.w + xi;
        op[c * 256 + tid] = v;
    }
}

extern "C" void kernel_launch(void* const* d_in, const int* in_sizes, int n_in,
                              void* d_out, int out_size, void* d_ws, size_t ws_size,
                              hipStream_t stream) {
    const float* x = (const float*)d_in[0];   // [IN_SZ]
    const float* u = (const float*)d_in[1];   // [OUT_SZ]
    const float* J = (const float*)d_in[2];   // [IN_SZ, OUT_SZ]
    const float* W = (const float*)d_in[3];   // [IN_SZ, OUT_SZ]
    float* out = (float*)d_out;

    const size_t ws_needed = (size_t)GEMV_CHUNKS * OUT_SZ * sizeof(float); // 4 MB

    if (d_ws != nullptr && ws_size >= ws_needed) {
        float* partial = (float*)d_ws;
        float* Jout = out + OUT_SZ;

        // A/B: same work, nt vs plain, separate dispatches for per-dispatch
        // counters. Serialized on the stream -> each gets the full machine.
        jup_half_kernel<true ><<<IN_SZ / 2, 256, 0, stream>>>(x, J, Jout, 0);
        jup_half_kernel<false><<<IN_SZ / 2, 256, 0, stream>>>(x, J, Jout, IN_SZ / 2);

        gemv_partial_kernel<<<GEMV_BLOCKS, 256, 0, stream>>>(x, W, partial);
        finalize_reduce_kernel<<<(OUT_SZ + 255) / 256, 256, 0, stream>>>(
            u, partial, out);
    } else {
        // fallback: previous verified 4-launch atomic path
        jup_kernel<<<IN_SZ, 256, 0, stream>>>(x, J, out + OUT_SZ);
        zeroI_kernel<<<(OUT_SZ + 255) / 256, 256, 0, stream>>>(out);
        gemv_partial_atomic_kernel<64><<<dim3(OUT_SZ / 1024, IN_SZ / 64), 256, 0, stream>>>(x, W, out);
        finalize_kernel<<<(OUT_SZ + 255) / 256, 256, 0, stream>>>(u, out);
    }
}